// Round 1
// baseline (87.359 us; speedup 1.0000x reference)
//
#include <hip/hip_runtime.h>
#include <math.h>

#define NB 16
#define NC 256
#define NH 64
#define NW 64
#define HALF 128
#define PLANE (NH*NW)   // 4096

// ws float layout
#define WS_WW   0       // 256 floats: softmax(dir_weight_w)
#define WS_WH   256     // 256 floats: softmax(dir_weight_h)
#define WS_GH   512     // NB*NH = 1024
#define WS_GW   1536    // NB*NW = 1024
#define WS_CONS 2560    // NB*NH*NW = 65536
#define WS_TOTAL 68096

__global__ __launch_bounds__(256) void k_softmax(const float* __restrict__ dwh,
                                                 const float* __restrict__ dww,
                                                 float* __restrict__ ws) {
    __shared__ float red[256];
    const int t = threadIdx.x;
    const float vh = dwh[t];
    const float vw = dww[t];

    // softmax of dir_weight_w -> ws[WS_WW]
    red[t] = vw; __syncthreads();
    for (int s = 128; s > 0; s >>= 1) { if (t < s) red[t] = fmaxf(red[t], red[t+s]); __syncthreads(); }
    const float mw = red[0]; __syncthreads();
    const float ew = expf(vw - mw);
    red[t] = ew; __syncthreads();
    for (int s = 128; s > 0; s >>= 1) { if (t < s) red[t] += red[t+s]; __syncthreads(); }
    const float sw = red[0]; __syncthreads();
    ws[WS_WW + t] = ew / sw;

    // softmax of dir_weight_h -> ws[WS_WH]
    red[t] = vh; __syncthreads();
    for (int s = 128; s > 0; s >>= 1) { if (t < s) red[t] = fmaxf(red[t], red[t+s]); __syncthreads(); }
    const float mh = red[0]; __syncthreads();
    const float eh = expf(vh - mh);
    red[t] = eh; __syncthreads();
    for (int s = 128; s > 0; s >>= 1) { if (t < s) red[t] += red[t+s]; __syncthreads(); }
    const float sh = red[0]; __syncthreads();
    ws[WS_WH + t] = eh / sh;
}

// One block per (b, channel-pair). Loads planes c and c+128 (32 KB),
// produces: row-sum contributions to gh, col-sum contributions to gw,
// and |3x3 boxsum(x1*x2)| contributions to cons.
__global__ __launch_bounds__(256) void k_reduce(const float* __restrict__ x,
                                                float* __restrict__ ws) {
    __shared__ float s1[PLANE];
    __shared__ float s2[PLANE];
    __shared__ float sp[PLANE];
    const int t   = threadIdx.x;
    const int blk = blockIdx.x;
    const int b   = blk >> 7;       // / 128
    const int c1  = blk & 127;
    const int c2  = c1 + HALF;

    const float wwc1 = ws[WS_WW + c1], wwc2 = ws[WS_WW + c2];
    const float whc1 = ws[WS_WH + c1], whc2 = ws[WS_WH + c2];
    float* gh   = ws + WS_GH;
    float* gw   = ws + WS_GW;
    float* cons = ws + WS_CONS;

    const float* p1 = x + ((size_t)(b*NC + c1)) * PLANE;
    const float* p2 = x + ((size_t)(b*NC + c2)) * PLANE;

    // thread t owns 16 consecutive floats of row (t>>2): offset 16*t
    const int off = t * 16;
    float4 a0, a1, a2, a3;
    {
        const float4* g = reinterpret_cast<const float4*>(p1 + off);
        a0 = g[0]; a1 = g[1]; a2 = g[2]; a3 = g[3];
    }
    float rs1 = (a0.x+a0.y+a0.z+a0.w)+(a1.x+a1.y+a1.z+a1.w)
              + (a2.x+a2.y+a2.z+a2.w)+(a3.x+a3.y+a3.z+a3.w);
    {
        float4* s = reinterpret_cast<float4*>(&s1[off]);
        s[0]=a0; s[1]=a1; s[2]=a2; s[3]=a3;
    }
    float4 b0, b1, b2, b3;
    {
        const float4* g = reinterpret_cast<const float4*>(p2 + off);
        b0 = g[0]; b1 = g[1]; b2 = g[2]; b3 = g[3];
    }
    float rs2 = (b0.x+b0.y+b0.z+b0.w)+(b1.x+b1.y+b1.z+b1.w)
              + (b2.x+b2.y+b2.z+b2.w)+(b3.x+b3.y+b3.z+b3.w);
    {
        float4* s = reinterpret_cast<float4*>(&s2[off]);
        s[0]=b0; s[1]=b1; s[2]=b2; s[3]=b3;
    }

    // full row sums: reduce over 4 lanes sharing a row (same wave)
    float rsum1 = rs1 + __shfl_xor(rs1, 1); rsum1 += __shfl_xor(rsum1, 2);
    float rsum2 = rs2 + __shfl_xor(rs2, 1); rsum2 += __shfl_xor(rsum2, 2);
    if ((t & 3) == 0)
        atomicAdd(&gh[b*NH + (t>>2)], (wwc1*rsum1 + wwc2*rsum2) * (1.0f/16384.0f));

    __syncthreads();

    // column sums (threads 0..63, consecutive-lane LDS reads: conflict-free)
    if (t < 64) {
        float cs1 = 0.f, cs2 = 0.f;
        #pragma unroll
        for (int r = 0; r < 64; ++r) { cs1 += s1[r*64 + t]; cs2 += s2[r*64 + t]; }
        atomicAdd(&gw[b*NW + t], (whc1*cs1 + whc2*cs2) * (1.0f/16384.0f));
    }

    // product plane
    #pragma unroll
    for (int i = 0; i < 16; ++i) { int p = i*256 + t; sp[p] = s1[p]*s2[p]; }
    __syncthreads();

    // 3x3 zero-padded box sum, abs, accumulate into cons
    const float scale = 1.0f / (9.0f * 128.0f);
    #pragma unroll
    for (int i = 0; i < 16; ++i) {
        int p = i*256 + t;
        int h = p >> 6, w = p & 63;
        int hlo = (h > 0) ? h-1 : 0, hhi = (h < 63) ? h+1 : 63;
        int wlo = (w > 0) ? w-1 : 0, whi = (w < 63) ? w+1 : 63;
        float s = 0.f;
        for (int hh = hlo; hh <= hhi; ++hh)
            for (int w2 = wlo; w2 <= whi; ++w2)
                s += sp[hh*64 + w2];
        atomicAdd(&cons[(b*NH + h)*NW + w], fabsf(s) * scale);
    }
}

__global__ __launch_bounds__(256) void k_apply(const float* __restrict__ x,
                                               const float* __restrict__ ws,
                                               const float* __restrict__ pgw,
                                               const float* __restrict__ pgb,
                                               float* __restrict__ out) {
    const float gateW = pgw[0];
    const float gateB = pgb[0];
    const float* gh   = ws + WS_GH;
    const float* gw   = ws + WS_GW;
    const float* cons = ws + WS_CONS;
    const long total4 = (long)NB*NC*NH*NW/4;   // 4,194,304
    const long stride = (long)gridDim.x * blockDim.x;
    for (long i = (long)blockIdx.x*blockDim.x + threadIdx.x; i < total4; i += stride) {
        const long e = i << 2;
        const int w = (int)(e & 63);            // multiple of 4
        const int h = (int)((e >> 6) & 63);
        const int b = (int)(e >> 20);           // C*H*W = 2^20

        const float4 xv  = reinterpret_cast<const float4*>(x)[i];
        const float4 cv  = *reinterpret_cast<const float4*>(&cons[((b<<6) + h)*64 + w]);
        const float4 gwv = *reinterpret_cast<const float4*>(&gw[(b<<6) + w]);
        const float ghv  = gh[(b<<6) + h];

        float4 o;
        float z;
        z = gateW * (ghv + gwv.x) * (1.f - fminf(fmaxf(cv.x, 0.f), 1.f)) + gateB;
        o.x = xv.x / (1.f + expf(-z));
        z = gateW * (ghv + gwv.y) * (1.f - fminf(fmaxf(cv.y, 0.f), 1.f)) + gateB;
        o.y = xv.y / (1.f + expf(-z));
        z = gateW * (ghv + gwv.z) * (1.f - fminf(fmaxf(cv.z, 0.f), 1.f)) + gateB;
        o.z = xv.z / (1.f + expf(-z));
        z = gateW * (ghv + gwv.w) * (1.f - fminf(fmaxf(cv.w, 0.f), 1.f)) + gateB;
        o.w = xv.w / (1.f + expf(-z));
        reinterpret_cast<float4*>(out)[i] = o;
    }
}

extern "C" void kernel_launch(void* const* d_in, const int* in_sizes, int n_in,
                              void* d_out, int out_size, void* d_ws, size_t ws_size,
                              hipStream_t stream) {
    const float* x   = (const float*)d_in[0];
    const float* dwh = (const float*)d_in[1];   // dir_weight_h
    const float* dww = (const float*)d_in[2];   // dir_weight_w
    const float* pgw = (const float*)d_in[3];   // gate_w (scalar)
    const float* pgb = (const float*)d_in[4];   // gate_b (scalar)
    float* out = (float*)d_out;
    float* ws  = (float*)d_ws;

    // zero the accumulators (gh, gw, cons); ww/wh are overwritten by k_softmax
    hipMemsetAsync(ws + WS_GH, 0, (size_t)(WS_TOTAL - WS_GH) * sizeof(float), stream);
    k_softmax<<<1, 256, 0, stream>>>(dwh, dww, ws);
    k_reduce<<<NB*HALF, 256, 0, stream>>>(x, ws);
    k_apply<<<2048, 256, 0, stream>>>(x, ws, pgw, pgb, out);
}

// Round 2
// 57.209 us; speedup vs baseline: 1.5270x; 1.5270x over previous
//
#include <hip/hip_runtime.h>
#include <math.h>

#define NB 16
#define NC 256
#define NH 64
#define NW 64
#define HALF 128
#define PLANE (NH*NW)   // 4096

// k_reduce tiling: 16-row stripes, 16 channel-groups of 8 pairs
#define HTILES 4
#define CG 16
#define PP 8

// ws float layout
#define WS_WW   0       // 256 floats: softmax(dir_weight_w)
#define WS_WH   256     // 256 floats: softmax(dir_weight_h)
#define WS_GH   512     // NB*NH = 1024
#define WS_GW   1536    // NB*NW = 1024
#define WS_CONS 2560    // NB*NH*NW = 65536
#define WS_TOTAL 68096

__global__ __launch_bounds__(256) void k_softmax(const float* __restrict__ dwh,
                                                 const float* __restrict__ dww,
                                                 float* __restrict__ ws) {
    __shared__ float red[256];
    const int t = threadIdx.x;
    const float vh = dwh[t];
    const float vw = dww[t];

    red[t] = vw; __syncthreads();
    for (int s = 128; s > 0; s >>= 1) { if (t < s) red[t] = fmaxf(red[t], red[t+s]); __syncthreads(); }
    const float mw = red[0]; __syncthreads();
    const float ew = expf(vw - mw);
    red[t] = ew; __syncthreads();
    for (int s = 128; s > 0; s >>= 1) { if (t < s) red[t] += red[t+s]; __syncthreads(); }
    const float sw = red[0]; __syncthreads();
    ws[WS_WW + t] = ew / sw;

    red[t] = vh; __syncthreads();
    for (int s = 128; s > 0; s >>= 1) { if (t < s) red[t] = fmaxf(red[t], red[t+s]); __syncthreads(); }
    const float mh = red[0]; __syncthreads();
    const float eh = expf(vh - mh);
    red[t] = eh; __syncthreads();
    for (int s = 128; s > 0; s >>= 1) { if (t < s) red[t] += red[t+s]; __syncthreads(); }
    const float sh = red[0]; __syncthreads();
    ws[WS_WH + t] = eh / sh;
}

// horizontal 3-tap sum of a float4 row-segment, neighbors via shuffle.
// fc==0 / fc==15 are the w=0 / w=63 plane edges -> zero pad.
__device__ __forceinline__ float4 hsum4(float4 p, int fc) {
    float pl = __shfl_up(p.w, 1);
    float pr = __shfl_down(p.x, 1);
    if (fc == 0)  pl = 0.f;
    if (fc == 15) pr = 0.f;
    float4 h;
    h.x = pl  + p.x + p.y;
    h.y = p.x + p.y + p.z;
    h.z = p.y + p.z + p.w;
    h.w = p.z + p.w + pr;
    return h;
}

__device__ __forceinline__ float sum4(float4 v) { return (v.x+v.y)+(v.z+v.w); }

// Block = (b, 16-row stripe, group of 8 channel pairs).
// Register-accumulated cons/gh/gw over the pair loop; one atomic per output at end.
__global__ __launch_bounds__(256) void k_reduce(const float* __restrict__ x,
                                                float* __restrict__ ws) {
    __shared__ float shs[18*64];   // hsum rows: 1 halo + 16 owned + 1 halo

    const int t   = threadIdx.x;
    const int r   = t >> 4;        // owned-row index 0..15
    const int fc  = t & 15;        // float4 column 0..15
    const int w   = t & 63;        // box-phase column
    const int rb  = (t >> 6) * 4;  // box-phase row base (wave-uniform)

    const int blk = blockIdx.x;
    const int b   = blk >> 6;
    const int ht  = (blk >> 4) & 3;
    const int cg  = blk & 15;
    const int h0  = ht * 16;

    const float* wsw = ws + WS_WW;
    const float* wsh = ws + WS_WH;
    float* gh   = ws + WS_GH;
    float* gw   = ws + WS_GW;
    float* cons = ws + WS_CONS;

    float ghacc = 0.f;
    float4 colacc = {0.f, 0.f, 0.f, 0.f};
    float consX = 0.f, consY = 0.f, consZ = 0.f, consW = 0.f;

    const bool doT = (t < 16);
    const bool doB = (t >= 240);

    #pragma unroll
    for (int pp = 0; pp < PP; ++pp) {
        const int c1 = cg * PP + pp;
        const int c2 = c1 + HALF;
        const float ww1 = wsw[c1], ww2 = wsw[c2];
        const float wh1 = wsh[c1], wh2 = wsh[c2];

        const float* p1 = x + ((size_t)(b*NC + c1)) * PLANE + h0 * NW;
        const float* p2 = x + ((size_t)(b*NC + c2)) * PLANE + h0 * NW;

        // owned rows: contiguous across the block (addr = 4t floats)
        const float4 x1v = reinterpret_cast<const float4*>(p1)[t];
        const float4 x2v = reinterpret_cast<const float4*>(p2)[t];
        float4 pr;
        pr.x = x1v.x * x2v.x; pr.y = x1v.y * x2v.y;
        pr.z = x1v.z * x2v.z; pr.w = x1v.w * x2v.w;
        const float4 hs = hsum4(pr, fc);

        // halo rows
        float4 hsT, hsB;
        if (doT) {
            float4 a = {0,0,0,0}, bb = {0,0,0,0};
            if (h0 > 0) {
                a  = *reinterpret_cast<const float4*>(p1 - NW + 4*t);
                bb = *reinterpret_cast<const float4*>(p2 - NW + 4*t);
            }
            float4 pt; pt.x = a.x*bb.x; pt.y = a.y*bb.y; pt.z = a.z*bb.z; pt.w = a.w*bb.w;
            hsT = hsum4(pt, fc);
        }
        if (doB) {
            float4 a = {0,0,0,0}, bb = {0,0,0,0};
            if (h0 + 16 < NH) {
                a  = *reinterpret_cast<const float4*>(p1 + 16*NW + 4*(t-240));
                bb = *reinterpret_cast<const float4*>(p2 + 16*NW + 4*(t-240));
            }
            float4 pt; pt.x = a.x*bb.x; pt.y = a.y*bb.y; pt.z = a.z*bb.z; pt.w = a.w*bb.w;
            hsB = hsum4(pt, fc);
        }

        __syncthreads();   // previous box-phase reads done
        reinterpret_cast<float4*>(shs)[t + 16] = hs;                 // row r+1
        if (doT) reinterpret_cast<float4*>(shs)[t] = hsT;            // row 0
        if (doB) reinterpret_cast<float4*>(shs)[272 + (t - 240)] = hsB; // row 17

        // gh: softmax_w-weighted row sums (reduce over 16 lanes of same row)
        float rs = ww1 * sum4(x1v) + ww2 * sum4(x2v);
        #pragma unroll
        for (int s2 = 1; s2 < 16; s2 <<= 1) rs += __shfl_xor(rs, s2);
        ghacc += rs;
        // gw: softmax_h-weighted column partials (register, per-w)
        colacc.x += wh1 * x1v.x + wh2 * x2v.x;
        colacc.y += wh1 * x1v.y + wh2 * x2v.y;
        colacc.z += wh1 * x1v.z + wh2 * x2v.z;
        colacc.w += wh1 * x1v.w + wh2 * x2v.w;

        __syncthreads();   // shs ready

        // vertical 3-tap: all lanes of a wave read the same row, consecutive w
        const float a0 = shs[(rb+0)*64 + w];
        const float a1 = shs[(rb+1)*64 + w];
        const float a2 = shs[(rb+2)*64 + w];
        const float a3 = shs[(rb+3)*64 + w];
        const float a4 = shs[(rb+4)*64 + w];
        const float a5 = shs[(rb+5)*64 + w];
        consX += fabsf(a0 + a1 + a2);
        consY += fabsf(a1 + a2 + a3);
        consZ += fabsf(a2 + a3 + a4);
        consW += fabsf(a3 + a4 + a5);
    }

    __syncthreads();   // protect last box reads before scol reuse
    reinterpret_cast<float4*>(shs)[t] = colacc;   // scol[r][4fc..]
    __syncthreads();

    if (t < 64) {
        float s = 0.f;
        #pragma unroll
        for (int r2 = 0; r2 < 16; ++r2) s += shs[r2*64 + t];
        atomicAdd(&gw[b*NW + t], s * (1.0f/16384.0f));
    }
    if (fc == 0)
        atomicAdd(&gh[b*NH + h0 + r], ghacc * (1.0f/16384.0f));

    const float SC = 1.0f / (9.0f * 128.0f);
    atomicAdd(&cons[((size_t)b*NH + h0 + rb + 0)*NW + w], consX * SC);
    atomicAdd(&cons[((size_t)b*NH + h0 + rb + 1)*NW + w], consY * SC);
    atomicAdd(&cons[((size_t)b*NH + h0 + rb + 2)*NW + w], consZ * SC);
    atomicAdd(&cons[((size_t)b*NH + h0 + rb + 3)*NW + w], consW * SC);
}

__global__ __launch_bounds__(256) void k_apply(const float* __restrict__ x,
                                               const float* __restrict__ ws,
                                               const float* __restrict__ pgw,
                                               const float* __restrict__ pgb,
                                               float* __restrict__ out) {
    const float gateW = pgw[0];
    const float gateB = pgb[0];
    const float* gh   = ws + WS_GH;
    const float* gw   = ws + WS_GW;
    const float* cons = ws + WS_CONS;
    const long total4 = (long)NB*NC*NH*NW/4;
    const long stride = (long)gridDim.x * blockDim.x;
    for (long i = (long)blockIdx.x*blockDim.x + threadIdx.x; i < total4; i += stride) {
        const long e = i << 2;
        const int w = (int)(e & 63);
        const int h = (int)((e >> 6) & 63);
        const int b = (int)(e >> 20);

        const float4 xv  = reinterpret_cast<const float4*>(x)[i];
        const float4 cv  = *reinterpret_cast<const float4*>(&cons[((b<<6) + h)*64 + w]);
        const float4 gwv = *reinterpret_cast<const float4*>(&gw[(b<<6) + w]);
        const float ghv  = gh[(b<<6) + h];

        float4 o;
        float z;
        z = gateW * (ghv + gwv.x) * (1.f - fminf(fmaxf(cv.x, 0.f), 1.f)) + gateB;
        o.x = xv.x / (1.f + expf(-z));
        z = gateW * (ghv + gwv.y) * (1.f - fminf(fmaxf(cv.y, 0.f), 1.f)) + gateB;
        o.y = xv.y / (1.f + expf(-z));
        z = gateW * (ghv + gwv.z) * (1.f - fminf(fmaxf(cv.z, 0.f), 1.f)) + gateB;
        o.z = xv.z / (1.f + expf(-z));
        z = gateW * (ghv + gwv.w) * (1.f - fminf(fmaxf(cv.w, 0.f), 1.f)) + gateB;
        o.w = xv.w / (1.f + expf(-z));
        reinterpret_cast<float4*>(out)[i] = o;
    }
}

extern "C" void kernel_launch(void* const* d_in, const int* in_sizes, int n_in,
                              void* d_out, int out_size, void* d_ws, size_t ws_size,
                              hipStream_t stream) {
    const float* x   = (const float*)d_in[0];
    const float* dwh = (const float*)d_in[1];
    const float* dww = (const float*)d_in[2];
    const float* pgw = (const float*)d_in[3];
    const float* pgb = (const float*)d_in[4];
    float* out = (float*)d_out;
    float* ws  = (float*)d_ws;

    hipMemsetAsync(ws + WS_GH, 0, (size_t)(WS_TOTAL - WS_GH) * sizeof(float), stream);
    k_softmax<<<1, 256, 0, stream>>>(dwh, dww, ws);
    k_reduce<<<NB*HTILES*CG, 256, 0, stream>>>(x, ws);
    k_apply<<<2048, 256, 0, stream>>>(x, ws, pgw, pgb, out);
}

// Round 3
// 52.373 us; speedup vs baseline: 1.6680x; 1.0923x over previous
//
#include <hip/hip_runtime.h>
#include <math.h>

#define NB 16
#define NC 256
#define NH 64
#define NW 64
#define HALF 128
#define PLANE (NH*NW)   // 4096

// k_reduce tiling: 16-row stripes, 16 channel-groups of 8 pairs
#define HTILES 4
#define CG 16
#define PP 8

// ws float layout
#define WS_WW   0       // 256 floats: softmax(dir_weight_w)
#define WS_WH   256     // 256 floats: softmax(dir_weight_h)
#define WS_GH   512     // NB*NH = 1024
#define WS_GW   1536    // NB*NW = 1024
#define WS_CONS 2560    // NB*NH*NW = 65536
#define WS_TOTAL 68096  // WS_GH + 67584 (67584 floats = 16896 float4 = 66*256)

// blocks 0..65: zero the accumulator region (gh/gw/cons).
// block 66: compute both channel softmaxes.
__global__ __launch_bounds__(256) void k_init(const float* __restrict__ dwh,
                                              const float* __restrict__ dww,
                                              float* __restrict__ ws) {
    const int t = threadIdx.x;
    if (blockIdx.x < 66) {
        float4 z = {0.f, 0.f, 0.f, 0.f};
        reinterpret_cast<float4*>(ws + WS_GH)[blockIdx.x * 256 + t] = z;
        return;
    }

    __shared__ float red[256];
    const float vh = dwh[t];
    const float vw = dww[t];

    red[t] = vw; __syncthreads();
    for (int s = 128; s > 0; s >>= 1) { if (t < s) red[t] = fmaxf(red[t], red[t+s]); __syncthreads(); }
    const float mw = red[0]; __syncthreads();
    const float ew = expf(vw - mw);
    red[t] = ew; __syncthreads();
    for (int s = 128; s > 0; s >>= 1) { if (t < s) red[t] += red[t+s]; __syncthreads(); }
    const float sw = red[0]; __syncthreads();
    ws[WS_WW + t] = ew / sw;

    red[t] = vh; __syncthreads();
    for (int s = 128; s > 0; s >>= 1) { if (t < s) red[t] = fmaxf(red[t], red[t+s]); __syncthreads(); }
    const float mh = red[0]; __syncthreads();
    const float eh = expf(vh - mh);
    red[t] = eh; __syncthreads();
    for (int s = 128; s > 0; s >>= 1) { if (t < s) red[t] += red[t+s]; __syncthreads(); }
    const float sh = red[0]; __syncthreads();
    ws[WS_WH + t] = eh / sh;
}

// horizontal 3-tap sum of a float4 row-segment, neighbors via shuffle.
// fc==0 / fc==15 are the w=0 / w=63 plane edges -> zero pad.
__device__ __forceinline__ float4 hsum4(float4 p, int fc) {
    float pl = __shfl_up(p.w, 1);
    float pr = __shfl_down(p.x, 1);
    if (fc == 0)  pl = 0.f;
    if (fc == 15) pr = 0.f;
    float4 h;
    h.x = pl  + p.x + p.y;
    h.y = p.x + p.y + p.z;
    h.z = p.y + p.z + p.w;
    h.w = p.z + p.w + pr;
    return h;
}

__device__ __forceinline__ float sum4(float4 v) { return (v.x+v.y)+(v.z+v.w); }

// Block = (b, 16-row stripe, group of 8 channel pairs).
// Register-accumulated cons/gh/gw over the pair loop; one atomic per output at end.
__global__ __launch_bounds__(256) void k_reduce(const float* __restrict__ x,
                                                float* __restrict__ ws) {
    __shared__ float shs[18*64];   // hsum rows: 1 halo + 16 owned + 1 halo

    const int t   = threadIdx.x;
    const int r   = t >> 4;        // owned-row index 0..15
    const int fc  = t & 15;        // float4 column 0..15
    const int w   = t & 63;        // box-phase column
    const int rb  = (t >> 6) * 4;  // box-phase row base (wave-uniform)

    const int blk = blockIdx.x;
    const int b   = blk >> 6;
    const int ht  = (blk >> 4) & 3;
    const int cg  = blk & 15;
    const int h0  = ht * 16;

    const float* wsw = ws + WS_WW;
    const float* wsh = ws + WS_WH;
    float* gh   = ws + WS_GH;
    float* gw   = ws + WS_GW;
    float* cons = ws + WS_CONS;

    float ghacc = 0.f;
    float4 colacc = {0.f, 0.f, 0.f, 0.f};
    float consX = 0.f, consY = 0.f, consZ = 0.f, consW = 0.f;

    const bool doT = (t < 16);
    const bool doB = (t >= 240);

    #pragma unroll
    for (int pp = 0; pp < PP; ++pp) {
        const int c1 = cg * PP + pp;
        const int c2 = c1 + HALF;
        const float ww1 = wsw[c1], ww2 = wsw[c2];
        const float wh1 = wsh[c1], wh2 = wsh[c2];

        const float* p1 = x + ((size_t)(b*NC + c1)) * PLANE + h0 * NW;
        const float* p2 = x + ((size_t)(b*NC + c2)) * PLANE + h0 * NW;

        // owned rows: contiguous across the block (addr = 4t floats)
        const float4 x1v = reinterpret_cast<const float4*>(p1)[t];
        const float4 x2v = reinterpret_cast<const float4*>(p2)[t];
        float4 pr;
        pr.x = x1v.x * x2v.x; pr.y = x1v.y * x2v.y;
        pr.z = x1v.z * x2v.z; pr.w = x1v.w * x2v.w;
        const float4 hs = hsum4(pr, fc);

        // halo rows
        float4 hsT, hsB;
        if (doT) {
            float4 a = {0,0,0,0}, bb = {0,0,0,0};
            if (h0 > 0) {
                a  = *reinterpret_cast<const float4*>(p1 - NW + 4*t);
                bb = *reinterpret_cast<const float4*>(p2 - NW + 4*t);
            }
            float4 pt; pt.x = a.x*bb.x; pt.y = a.y*bb.y; pt.z = a.z*bb.z; pt.w = a.w*bb.w;
            hsT = hsum4(pt, fc);
        }
        if (doB) {
            float4 a = {0,0,0,0}, bb = {0,0,0,0};
            if (h0 + 16 < NH) {
                a  = *reinterpret_cast<const float4*>(p1 + 16*NW + 4*(t-240));
                bb = *reinterpret_cast<const float4*>(p2 + 16*NW + 4*(t-240));
            }
            float4 pt; pt.x = a.x*bb.x; pt.y = a.y*bb.y; pt.z = a.z*bb.z; pt.w = a.w*bb.w;
            hsB = hsum4(pt, fc);
        }

        __syncthreads();   // previous box-phase reads done
        reinterpret_cast<float4*>(shs)[t + 16] = hs;                 // row r+1
        if (doT) reinterpret_cast<float4*>(shs)[t] = hsT;            // row 0
        if (doB) reinterpret_cast<float4*>(shs)[272 + (t - 240)] = hsB; // row 17

        // gh: softmax_w-weighted row sums (reduce over 16 lanes of same row)
        float rs = ww1 * sum4(x1v) + ww2 * sum4(x2v);
        #pragma unroll
        for (int s2 = 1; s2 < 16; s2 <<= 1) rs += __shfl_xor(rs, s2);
        ghacc += rs;
        // gw: softmax_h-weighted column partials (register, per-w)
        colacc.x += wh1 * x1v.x + wh2 * x2v.x;
        colacc.y += wh1 * x1v.y + wh2 * x2v.y;
        colacc.z += wh1 * x1v.z + wh2 * x2v.z;
        colacc.w += wh1 * x1v.w + wh2 * x2v.w;

        __syncthreads();   // shs ready

        // vertical 3-tap: all lanes of a wave read the same row, consecutive w
        const float a0 = shs[(rb+0)*64 + w];
        const float a1 = shs[(rb+1)*64 + w];
        const float a2 = shs[(rb+2)*64 + w];
        const float a3 = shs[(rb+3)*64 + w];
        const float a4 = shs[(rb+4)*64 + w];
        const float a5 = shs[(rb+5)*64 + w];
        consX += fabsf(a0 + a1 + a2);
        consY += fabsf(a1 + a2 + a3);
        consZ += fabsf(a2 + a3 + a4);
        consW += fabsf(a3 + a4 + a5);
    }

    __syncthreads();   // protect last box reads before scol reuse
    reinterpret_cast<float4*>(shs)[t] = colacc;   // scol[r][4fc..]
    __syncthreads();

    if (t < 64) {
        float s = 0.f;
        #pragma unroll
        for (int r2 = 0; r2 < 16; ++r2) s += shs[r2*64 + t];
        atomicAdd(&gw[b*NW + t], s * (1.0f/16384.0f));
    }
    if (fc == 0)
        atomicAdd(&gh[b*NH + h0 + r], ghacc * (1.0f/16384.0f));

    const float SC = 1.0f / (9.0f * 128.0f);
    atomicAdd(&cons[((size_t)b*NH + h0 + rb + 0)*NW + w], consX * SC);
    atomicAdd(&cons[((size_t)b*NH + h0 + rb + 1)*NW + w], consY * SC);
    atomicAdd(&cons[((size_t)b*NH + h0 + rb + 2)*NW + w], consZ * SC);
    atomicAdd(&cons[((size_t)b*NH + h0 + rb + 3)*NW + w], consW * SC);
}

__global__ __launch_bounds__(256) void k_apply(const float* __restrict__ x,
                                               const float* __restrict__ ws,
                                               const float* __restrict__ pgw,
                                               const float* __restrict__ pgb,
                                               float* __restrict__ out) {
    const float gateW = pgw[0];
    const float gateB = pgb[0];
    const float* gh   = ws + WS_GH;
    const float* gw   = ws + WS_GW;
    const float* cons = ws + WS_CONS;
    const long total4 = (long)NB*NC*NH*NW/4;
    const long stride = (long)gridDim.x * blockDim.x;
    for (long i = (long)blockIdx.x*blockDim.x + threadIdx.x; i < total4; i += stride) {
        const long e = i << 2;
        const int w = (int)(e & 63);
        const int h = (int)((e >> 6) & 63);
        const int b = (int)(e >> 20);

        const float4 xv  = reinterpret_cast<const float4*>(x)[i];
        const float4 cv  = *reinterpret_cast<const float4*>(&cons[((b<<6) + h)*64 + w]);
        const float4 gwv = *reinterpret_cast<const float4*>(&gw[(b<<6) + w]);
        const float ghv  = gh[(b<<6) + h];

        float4 o;
        float z;
        z = gateW * (ghv + gwv.x) * (1.f - fminf(fmaxf(cv.x, 0.f), 1.f)) + gateB;
        o.x = xv.x / (1.f + expf(-z));
        z = gateW * (ghv + gwv.y) * (1.f - fminf(fmaxf(cv.y, 0.f), 1.f)) + gateB;
        o.y = xv.y / (1.f + expf(-z));
        z = gateW * (ghv + gwv.z) * (1.f - fminf(fmaxf(cv.z, 0.f), 1.f)) + gateB;
        o.z = xv.z / (1.f + expf(-z));
        z = gateW * (ghv + gwv.w) * (1.f - fminf(fmaxf(cv.w, 0.f), 1.f)) + gateB;
        o.w = xv.w / (1.f + expf(-z));
        reinterpret_cast<float4*>(out)[i] = o;
    }
}

extern "C" void kernel_launch(void* const* d_in, const int* in_sizes, int n_in,
                              void* d_out, int out_size, void* d_ws, size_t ws_size,
                              hipStream_t stream) {
    const float* x   = (const float*)d_in[0];
    const float* dwh = (const float*)d_in[1];
    const float* dww = (const float*)d_in[2];
    const float* pgw = (const float*)d_in[3];
    const float* pgb = (const float*)d_in[4];
    float* out = (float*)d_out;
    float* ws  = (float*)d_ws;

    k_init<<<67, 256, 0, stream>>>(dwh, dww, ws);
    k_reduce<<<NB*HTILES*CG, 256, 0, stream>>>(x, ws);
    k_apply<<<2048, 256, 0, stream>>>(x, ws, pgw, pgb, out);
}